// Round 14
// baseline (808.417 us; speedup 1.0000x reference)
//
#include <hip/hip_runtime.h>
#include <stdint.h>

#define N 8192
#define D 512
#define NEG -1e30f

typedef _Float16 f16;
typedef f16 f16x4 __attribute__((ext_vector_type(4)));
typedef f16 f16x8 __attribute__((ext_vector_type(8)));
typedef float f32x4v __attribute__((ext_vector_type(4)));
typedef float f32x16 __attribute__((ext_vector_type(16)));
typedef unsigned long long u64;

// ---- workspace layout (bytes) ----
#define XH_OFF   0ull
#define WQH_OFF  (XH_OFF + 8192ull * 512 * 2)
#define WKH_OFF  (WQH_OFF + 512ull * 512 * 2)
#define WVH_OFF  (WKH_OFF + 512ull * 512 * 2)
#define QH_OFF   (WVH_OFF + 512ull * 512 * 2)
#define KH_OFF   (QH_OFF + 8192ull * 512 * 2)
#define VT_OFF   (KH_OFF + 8192ull * 512 * 2)
#define PART_SZ  (8192ull * 512 * 2)                // one fp16 partial, 8 MB
#define P123_OFF (VT_OFF + 8192ull * 512 * 2)
#define ML_SZ    (4ull * N * 8)                     // float2[4][N]
#define ADJ_SZ   (128ull * N * 8)                   // u64 bitmap, 8 MB

#define PROW 144                                    // P slab row stride (16B-aligned, bank-spread)

// ---------------- fp32 -> fp16 conversion ----------------
__global__ __launch_bounds__(256) void cvt_fp16(
    const float* __restrict__ X,
    const float* __restrict__ Wq, const float* __restrict__ Wk, const float* __restrict__ Wv,
    f16* __restrict__ Xh,
    f16* __restrict__ Wqh, f16* __restrict__ Wkh, f16* __restrict__ Wvh)
{
    const int idx = blockIdx.x * 256 + threadIdx.x;
    const float* src; f16* dst; int off;
    if (idx < 1048576)      { src = X;  dst = Xh;  off = idx; }
    else if (idx < 1114112) { src = Wq; dst = Wqh; off = idx - 1048576; }
    else if (idx < 1179648) { src = Wk; dst = Wkh; off = idx - 1114112; }
    else                    { src = Wv; dst = Wvh; off = idx - 1179648; }
    const float4 v = ((const float4*)src)[off];
    f16x4 h; h.x = (f16)v.x; h.y = (f16)v.y; h.z = (f16)v.z; h.w = (f16)v.w;
    *(f16x4*)(dst + (size_t)off * 4) = h;
}

// ---------------- QKV via MFMA (unchanged) ----------------
__global__ __launch_bounds__(256) void qkv_mfma(
    const f16* __restrict__ Xh,
    const f16* __restrict__ Wqh, const f16* __restrict__ Wkh, const f16* __restrict__ Wvh,
    f16* __restrict__ qh, f16* __restrict__ kh, f16* __restrict__ vt)
{
    const int t    = threadIdx.x;
    const int w    = t >> 6;
    const int lane = t & 63;
    const int lo   = lane & 31;
    const int hi   = lane >> 5;
    const int z    = blockIdx.z;

    int m0, c0; const f16 *Ap, *Bp; f16* Yp; size_t ldy;
    if (z == 2) {
        m0 = blockIdx.x * 128 + w * 32; c0 = blockIdx.y * 128;
        Ap = Wvh; Bp = Xh; Yp = vt; ldy = N;
    } else {
        m0 = blockIdx.y * 128 + w * 32; c0 = blockIdx.x * 128;
        Ap = Xh; Bp = z ? Wkh : Wqh; Yp = z ? kh : qh; ldy = D;
    }

    const f16* arow = Ap + (size_t)(m0 + lo) * D + hi * 8;
    const f16* brow[4];
#pragma unroll
    for (int nn = 0; nn < 4; ++nn)
        brow[nn] = Bp + (size_t)(c0 + nn * 32 + lo) * D + hi * 8;

    f32x16 acc[4];
#pragma unroll
    for (int nn = 0; nn < 4; ++nn)
#pragma unroll
        for (int e = 0; e < 16; ++e) acc[nn][e] = 0.f;

#pragma unroll 4
    for (int ks = 0; ks < 32; ++ks) {
        const f16x8 a = *(const f16x8*)(arow + ks * 16);
#pragma unroll
        for (int nn = 0; nn < 4; ++nn) {
            const f16x8 b = *(const f16x8*)(brow[nn] + ks * 16);
            acc[nn] = __builtin_amdgcn_mfma_f32_32x32x16_f16(a, b, acc[nn], 0, 0, 0);
        }
    }

#pragma unroll
    for (int nn = 0; nn < 4; ++nn)
#pragma unroll
        for (int r = 0; r < 16; ++r) {
            const int row = m0 + (r & 3) + 8 * (r >> 2) + 4 * hi;
            Yp[(size_t)row * ldy + c0 + nn * 32 + lo] = (f16)acc[nn][r];
        }
}

// ---------------- adjacency bit-pack, COALESCED (r13) ----------------
__global__ __launch_bounds__(256) void pack_adj(
    const int* __restrict__ adj, u64* __restrict__ adjb)
{
    const int idx = blockIdx.x * 256 + threadIdx.x;   // 1,048,576 total
    const int j   = idx & (N - 1);
    const int iw  = idx >> 13;                        // 0..127
    const int* src = adj + (size_t)iw * 64 * N + j;
    u64 bits = 0;
#pragma unroll 8
    for (int i2 = 0; i2 < 64; ++i2)
        bits |= (u64)(src[(size_t)i2 * N] != 0) << i2;
    adjb[(size_t)iw * N + j] = bits;
}

// ---------------- attention v8: Q-in-regs, wave-private softmax, 2 barriers ----------------
// grid = 128 j-tiles (BJ=64) x nib i-blocks = 512 blocks, 256 thr / 4 waves, 2/CU.
// QK^T: wave w owns j-band w*16 END-TO-END (Q frags in 64 VGPRs, K read by all
// waves, softmax wave-private: lane = column j, shfl_xor(16,32) row-reduce).
// PV: wave w owns d-band w*128 (P via 9 KB LDS slab; O-rescale factors via scl).
// Only 2 barriers/tile; no Qs LDS, no stats exchange, no combine phase.
__global__ __launch_bounds__(256, 2) void attn_v8(
    const f16* __restrict__ qh, const f16* __restrict__ kh,
    const f16* __restrict__ vt, const u64* __restrict__ adjb,
    f16* __restrict__ part0, f16* __restrict__ part123, float2* __restrict__ ml)
{
    __shared__ char  Psb[64 * PROW];    // 9,216 B
    __shared__ float scl[64];

    const int t  = threadIdx.x;
    const int w  = t >> 6;
    const int l  = t & 63;
    const int cl = l & 15;
    const int hq = l >> 4;

    // XCD-aware mapping (v4.1's proven layout)
    const int nib = gridDim.x >> 7;          // 4 or 2
    const int b   = blockIdx.x;
    const int xcd = b & 7;
    int ib, jt_;
    if (nib == 4) { ib = xcd >> 1; jt_ = (xcd & 1) * 64 + (b >> 3); }
    else          { ib = xcd >> 2; jt_ = (xcd & 3) * 32 + (b >> 3); }
    const int j0    = jt_ * 64;
    const int ibase = ib * (N / nib);
    const int iters = (N / nib) >> 6;

    f16* pb = (ib == 0) ? part0 : part123 + (size_t)(ib - 1) * ((size_t)N * D);

    // ---- Q fragments into registers (once): my j = j0 + w*16 + cl ----
    const int jmine = j0 + w * 16 + cl;
    f16x8 qreg[16];
    {
        const f16* qp = qh + (size_t)jmine * D + hq * 8;
#pragma unroll
        for (int ks = 0; ks < 16; ++ks) qreg[ks] = *(const f16x8*)(qp + ks * 32);
    }

    float m_run = NEG, l_run = 0.f;          // stats for column jmine (consistent across hq)

    f32x4v oacc[4][8];
#pragma unroll
    for (int jt = 0; jt < 4; ++jt)
#pragma unroll
        for (int dt = 0; dt < 8; ++dt) {
            oacc[jt][dt][0] = 0.f; oacc[jt][dt][1] = 0.f;
            oacc[jt][dt][2] = 0.f; oacc[jt][dt][3] = 0.f;
        }

    for (int it = 0; it < iters; ++it) {
        const int i0t = ibase + it * 64;

        // ---- mask bits for my column: one u64 (i0t..i0t+63) ----
        const u64 wd = adjb[((size_t)(i0t >> 6)) * N + jmine];

        // ---- QK^T: S^T[i 64][j = my 16], A=K (global 16-line loads), B=Q regs ----
        f32x4v sacc[4];
#pragma unroll
        for (int it2 = 0; it2 < 4; ++it2) {
            sacc[it2][0] = 0.f; sacc[it2][1] = 0.f; sacc[it2][2] = 0.f; sacc[it2][3] = 0.f;
        }
        const f16* kp = kh + (size_t)(i0t + cl) * D + hq * 8;
#pragma unroll
        for (int ks = 0; ks < 16; ++ks) {
            f16x8 kf[4];
#pragma unroll
            for (int it2 = 0; it2 < 4; ++it2)
                kf[it2] = *(const f16x8*)(kp + (size_t)(it2 * 16) * D + ks * 32);
#pragma unroll
            for (int it2 = 0; it2 < 4; ++it2)
                sacc[it2] = __builtin_amdgcn_mfma_f32_16x16x32_f16(kf[it2], qreg[ks], sacc[it2], 0, 0, 0);
        }

        // ---- wave-private masked online softmax (column j = jmine) ----
        // lane holds S^T[i = i0t + it2*16 + hq*4 + r][jmine]
        float s[4][4];
        float mt = NEG;
#pragma unroll
        for (int it2 = 0; it2 < 4; ++it2)
#pragma unroll
            for (int r = 0; r < 4; ++r) {
                const float sv = ((wd >> (it2 * 16 + hq * 4 + r)) & 1) ? sacc[it2][r] : NEG;
                s[it2][r] = sv;
                mt = fmaxf(mt, sv);
            }
        mt = fmaxf(mt, __shfl_xor(mt, 16, 64));
        mt = fmaxf(mt, __shfl_xor(mt, 32, 64));

        const float m_new = fmaxf(m_run, mt);
        const float sc = __expf(m_run - m_new);
        m_run = m_new;

        float ps = 0.f;
        float pe[4][4];
#pragma unroll
        for (int it2 = 0; it2 < 4; ++it2)
#pragma unroll
            for (int r = 0; r < 4; ++r) {
                const float p = (s[it2][r] > -1e29f) ? __expf(s[it2][r] - m_run) : 0.f;
                pe[it2][r] = p;
                ps += p;
            }
        ps += __shfl_xor(ps, 16, 64);
        ps += __shfl_xor(ps, 32, 64);
        l_run = l_run * sc + ps;

        // ---- write P[j = w*16+cl][i] + rescale factor ----
#pragma unroll
        for (int it2 = 0; it2 < 4; ++it2) {
            union { f16 h[4]; uint2 u2; } pc;
#pragma unroll
            for (int r = 0; r < 4; ++r) pc.h[r] = (f16)pe[it2][r];
            *(uint2*)(Psb + (w * 16 + cl) * PROW + (it2 * 16 + hq * 4) * 2) = pc.u2;
        }
        if (hq == 0) scl[w * 16 + cl] = sc;
        __syncthreads();                     // [A] P + scl ready

        // ---- PV: wave w = d-band w*128; rescale O by scl[j] first ----
#pragma unroll
        for (int jt = 0; jt < 4; ++jt) {
#pragma unroll
            for (int r = 0; r < 4; ++r) {
                const float scr = scl[jt * 16 + hq * 4 + r];
#pragma unroll
                for (int dt = 0; dt < 8; ++dt) oacc[jt][dt][r] *= scr;
            }
        }

        f16x8 pa[4][2];
#pragma unroll
        for (int jt = 0; jt < 4; ++jt)
#pragma unroll
            for (int k2 = 0; k2 < 2; ++k2)
                pa[jt][k2] = *(const f16x8*)(Psb + (jt * 16 + cl) * PROW + k2 * 64 + hq * 16);

#pragma unroll
        for (int dt = 0; dt < 8; ++dt) {
            const f16* vp = vt + (size_t)(w * 128 + dt * 16 + cl) * N + i0t + hq * 8;
#pragma unroll
            for (int k2 = 0; k2 < 2; ++k2) {
                const f16x8 vf = *(const f16x8*)(vp + k2 * 32);
#pragma unroll
                for (int jt = 0; jt < 4; ++jt)
                    oacc[jt][dt] = __builtin_amdgcn_mfma_f32_16x16x32_f16(pa[jt][k2], vf, oacc[jt][dt], 0, 0, 0);
            }
        }
        __syncthreads();                     // [B] P consumed
    }

    // ---- store fp16 unnormalized partial: row j = jt*16+hq*4+r, col = w*128+dt*16+cl ----
#pragma unroll
    for (int jt = 0; jt < 4; ++jt)
#pragma unroll
        for (int dt = 0; dt < 8; ++dt)
#pragma unroll
            for (int r = 0; r < 4; ++r)
                pb[(size_t)(j0 + jt * 16 + hq * 4 + r) * D + w * 128 + dt * 16 + cl] =
                    (f16)oacc[jt][dt][r];
    if (hq == 0) {
        float2 v; v.x = m_run; v.y = l_run;
        ml[(size_t)ib * N + jmine] = v;
    }
}

// ---------------- merge the i-block partials ----------------
__global__ __launch_bounds__(256) void merge_p(
    float* __restrict__ out, const f16* __restrict__ p0,
    const f16* __restrict__ p123, const float2* __restrict__ ml, int nib)
{
    const int idx = blockIdx.x * 256 + threadIdx.x;
    const int j = idx >> 7;
    const int col = (idx & 127) * 4;

    float m_g = NEG;
    for (int ib = 0; ib < nib; ++ib) m_g = fmaxf(m_g, ml[(size_t)ib * N + j].x);
    float L = 0.f;
    float4 acc; acc.x = 0.f; acc.y = 0.f; acc.z = 0.f; acc.w = 0.f;
    for (int ib = 0; ib < nib; ++ib) {
        const float2 a = ml[(size_t)ib * N + j];
        const float e = __expf(a.x - m_g);
        L += e * a.y;
        const f16* pp = (ib == 0) ? p0 : p123 + (size_t)(ib - 1) * ((size_t)N * D);
        const f16x4 h = *(const f16x4*)(pp + (size_t)j * D + col);
        acc.x += e * (float)h.x; acc.y += e * (float)h.y;
        acc.z += e * (float)h.z; acc.w += e * (float)h.w;
    }
    const float inv = (L > 0.f) ? 1.f / L : 0.f;
    float4 r; r.x = acc.x * inv; r.y = acc.y * inv; r.z = acc.z * inv; r.w = acc.w * inv;
    ((float4*)out)[idx] = r;
}

extern "C" void kernel_launch(void* const* d_in, const int* in_sizes, int n_in,
                              void* d_out, int out_size, void* d_ws, size_t ws_size,
                              hipStream_t stream) {
    const float* ns  = (const float*)d_in[0];
    const int*   adj = (const int*)d_in[1];
    const float* Wq  = (const float*)d_in[2];
    const float* Wk  = (const float*)d_in[3];
    const float* Wv  = (const float*)d_in[4];

    char* ws = (char*)d_ws;
    f16*   Xh   = (f16*)(ws + XH_OFF);
    f16*   Wqh  = (f16*)(ws + WQH_OFF);
    f16*   Wkh  = (f16*)(ws + WKH_OFF);
    f16*   Wvh  = (f16*)(ws + WVH_OFF);
    f16*   qh   = (f16*)(ws + QH_OFF);
    f16*   kh   = (f16*)(ws + KH_OFF);
    f16*   vt   = (f16*)(ws + VT_OFF);
    f16*   p0   = (f16*)(ws + XH_OFF);          // overlays dead XH
    f16*   p123 = (f16*)(ws + P123_OFF);
    float* out  = (float*)d_out;

    const size_t need4 = P123_OFF + 3 * PART_SZ + ML_SZ + ADJ_SZ;
    int nib; size_t ml_off;
    if (ws_size >= need4) { nib = 4; ml_off = P123_OFF + 3 * PART_SZ; }
    else                  { nib = 2; ml_off = P123_OFF + 1 * PART_SZ; }
    float2* mlb  = (float2*)(ws + ml_off);
    u64*    adjb = (u64*)(ws + ml_off + ML_SZ);

    cvt_fp16<<<4864, 256, 0, stream>>>(ns, Wq, Wk, Wv, Xh, Wqh, Wkh, Wvh);
    qkv_mfma<<<dim3(4, 64, 3), 256, 0, stream>>>(Xh, Wqh, Wkh, Wvh, qh, kh, vt);
    pack_adj<<<4096, 256, 0, stream>>>(adj, adjb);
    attn_v8<<<128 * nib, 256, 0, stream>>>(qh, kh, vt, adjb, p0, p123, mlb);
    merge_p<<<4096, 256, 0, stream>>>(out, p0, p123, mlb, nib);
}

// Round 15
// 514.703 us; speedup vs baseline: 1.5706x; 1.5706x over previous
//
#include <hip/hip_runtime.h>
#include <stdint.h>

#define N 8192
#define D 512
#define NEG -1e30f

typedef _Float16 f16;
typedef f16 f16x4 __attribute__((ext_vector_type(4)));
typedef f16 f16x8 __attribute__((ext_vector_type(8)));
typedef float f32x4v __attribute__((ext_vector_type(4)));
typedef float f32x16 __attribute__((ext_vector_type(16)));
typedef unsigned long long u64;

// ---- workspace layout (bytes) ----
#define XH_OFF   0ull
#define WQH_OFF  (XH_OFF + 8192ull * 512 * 2)
#define WKH_OFF  (WQH_OFF + 512ull * 512 * 2)
#define WVH_OFF  (WKH_OFF + 512ull * 512 * 2)
#define QH_OFF   (WVH_OFF + 512ull * 512 * 2)
#define KH_OFF   (QH_OFF + 8192ull * 512 * 2)
#define VT_OFF   (KH_OFF + 8192ull * 512 * 2)
#define PART_SZ  (8192ull * 512 * 2)                // one fp16 partial, 8 MB
#define P123_OFF (VT_OFF + 8192ull * 512 * 2)
#define ML_SZ    (4ull * N * 8)                     // float2[4][N]
#define ADJ_SZ   (128ull * N * 8)                   // u64 bitmap, 8 MB

// ---- attn_v9 LDS map (77,568 B dynamic -> 2 blocks/CU) ----
#define QROW     1040
#define PROW     144
#define PSB_OFF  66560                    // 64*1040
#define MST_OFF  75776                    // [2][64] f32
#define LST_OFF  76288
#define MROW_OFF 76800
#define LROW_OFF 77056
#define SCL_OFF  77312
#define LDSB_V9  77568

// ---------------- fp32 -> fp16 conversion ----------------
__global__ __launch_bounds__(256) void cvt_fp16(
    const float* __restrict__ X,
    const float* __restrict__ Wq, const float* __restrict__ Wk, const float* __restrict__ Wv,
    f16* __restrict__ Xh,
    f16* __restrict__ Wqh, f16* __restrict__ Wkh, f16* __restrict__ Wvh)
{
    const int idx = blockIdx.x * 256 + threadIdx.x;
    const float* src; f16* dst; int off;
    if (idx < 1048576)      { src = X;  dst = Xh;  off = idx; }
    else if (idx < 1114112) { src = Wq; dst = Wqh; off = idx - 1048576; }
    else if (idx < 1179648) { src = Wk; dst = Wkh; off = idx - 1114112; }
    else                    { src = Wv; dst = Wvh; off = idx - 1179648; }
    const float4 v = ((const float4*)src)[off];
    f16x4 h; h.x = (f16)v.x; h.y = (f16)v.y; h.z = (f16)v.z; h.w = (f16)v.w;
    *(f16x4*)(dst + (size_t)off * 4) = h;
}

// ---------------- QKV via MFMA (unchanged) ----------------
__global__ __launch_bounds__(256) void qkv_mfma(
    const f16* __restrict__ Xh,
    const f16* __restrict__ Wqh, const f16* __restrict__ Wkh, const f16* __restrict__ Wvh,
    f16* __restrict__ qh, f16* __restrict__ kh, f16* __restrict__ vt)
{
    const int t    = threadIdx.x;
    const int w    = t >> 6;
    const int lane = t & 63;
    const int lo   = lane & 31;
    const int hi   = lane >> 5;
    const int z    = blockIdx.z;

    int m0, c0; const f16 *Ap, *Bp; f16* Yp; size_t ldy;
    if (z == 2) {
        m0 = blockIdx.x * 128 + w * 32; c0 = blockIdx.y * 128;
        Ap = Wvh; Bp = Xh; Yp = vt; ldy = N;
    } else {
        m0 = blockIdx.y * 128 + w * 32; c0 = blockIdx.x * 128;
        Ap = Xh; Bp = z ? Wkh : Wqh; Yp = z ? kh : qh; ldy = D;
    }

    const f16* arow = Ap + (size_t)(m0 + lo) * D + hi * 8;
    const f16* brow[4];
#pragma unroll
    for (int nn = 0; nn < 4; ++nn)
        brow[nn] = Bp + (size_t)(c0 + nn * 32 + lo) * D + hi * 8;

    f32x16 acc[4];
#pragma unroll
    for (int nn = 0; nn < 4; ++nn)
#pragma unroll
        for (int e = 0; e < 16; ++e) acc[nn][e] = 0.f;

#pragma unroll 4
    for (int ks = 0; ks < 32; ++ks) {
        const f16x8 a = *(const f16x8*)(arow + ks * 16);
#pragma unroll
        for (int nn = 0; nn < 4; ++nn) {
            const f16x8 b = *(const f16x8*)(brow[nn] + ks * 16);
            acc[nn] = __builtin_amdgcn_mfma_f32_32x32x16_f16(a, b, acc[nn], 0, 0, 0);
        }
    }

#pragma unroll
    for (int nn = 0; nn < 4; ++nn)
#pragma unroll
        for (int r = 0; r < 16; ++r) {
            const int row = m0 + (r & 3) + 8 * (r >> 2) + 4 * hi;
            Yp[(size_t)row * ldy + c0 + nn * 32 + lo] = (f16)acc[nn][r];
        }
}

// ---------------- adjacency bit-pack, COALESCED (r13) ----------------
__global__ __launch_bounds__(256) void pack_adj(
    const int* __restrict__ adj, u64* __restrict__ adjb)
{
    const int idx = blockIdx.x * 256 + threadIdx.x;   // 1,048,576 total
    const int j   = idx & (N - 1);
    const int iw  = idx >> 13;                        // 0..127
    const int* src = adj + (size_t)iw * 64 * N + j;
    u64 bits = 0;
#pragma unroll 8
    for (int i2 = 0; i2 < 64; ++i2)
        bits |= (u64)(src[(size_t)i2 * N] != 0) << i2;
    adjb[(size_t)iw * N + j] = bits;
}

// ---------------- attention v9: v4.1 structure, 32x32x16 MFMA + bitmap ----------------
// grid = 128 j-tiles (BJ=64) x nib i-blocks = 512 blocks, 256 thr / 4 waves, 2/CU.
// Per tile (BI=64): wave w=(ih=w>>1, jh=w&1) computes S^T subtile [ih*32 i][jh*32 j]
// (A=K global 32-row, B=Q LDS). Softmax: in-lane 16 + shfl_xor(32); 2-band stats
// combine by wave 0 (v4.1 pattern). PV: wave w = d-band w*128, 8 C-tiles
// (2 jh x 4 dsub), A=P LDS, B=V^T global. 4 barriers/tile.
// 32x32x16 layout: A[row=l&31][k=(l>>5)*8+e], B[k][col=l&31],
//                  C[row=(r&3)+8*(r>>2)+4*(l>>5)][col=l&31].
__global__ __launch_bounds__(256, 2) void attn_v9(
    const f16* __restrict__ qh, const f16* __restrict__ kh,
    const f16* __restrict__ vt, const u64* __restrict__ adjb,
    f16* __restrict__ part0, f16* __restrict__ part123, float2* __restrict__ ml)
{
    extern __shared__ char smem[];
    char*  Qs    = smem;
    char*  Psb   = smem + PSB_OFF;
    float* mstat = (float*)(smem + MST_OFF);
    float* lstat = (float*)(smem + LST_OFF);
    float* mrow  = (float*)(smem + MROW_OFF);
    float* lrow  = (float*)(smem + LROW_OFF);
    float* scl   = (float*)(smem + SCL_OFF);

    const int t  = threadIdx.x;
    const int w  = t >> 6;
    const int l  = t & 63;
    const int lo = l & 31;
    const int hi = l >> 5;
    const int ih = w >> 1;
    const int jh = w & 1;

    // XCD-aware mapping (v4.1's proven layout)
    const int nib = gridDim.x >> 7;          // 4 or 2
    const int b   = blockIdx.x;
    const int xcd = b & 7;
    int ib, jt_;
    if (nib == 4) { ib = xcd >> 1; jt_ = (xcd & 1) * 64 + (b >> 3); }
    else          { ib = xcd >> 2; jt_ = (xcd & 3) * 32 + (b >> 3); }
    const int j0    = jt_ * 64;
    const int ibase = ib * (N / nib);
    const int iters = (N / nib) >> 6;

    f16* pb = (ib == 0) ? part0 : part123 + (size_t)(ib - 1) * ((size_t)N * D);

    // ---- stage Q[j0..j0+63] (row stride 1040) ----
    for (int c = t; c < 64 * 64; c += 256) {
        const int row = c >> 6, off = c & 63;
        f16x8 v = *(const f16x8*)(qh + (size_t)(j0 + row) * D + off * 8);
        *(f16x8*)(Qs + row * QROW + off * 16) = v;
    }
    if (t < 64) { mrow[t] = NEG; lrow[t] = 0.f; }
    __syncthreads();

    f32x16 oacc[2][4];                       // [jh2][dsub], 128 VGPR
#pragma unroll
    for (int a = 0; a < 2; ++a)
#pragma unroll
        for (int d2 = 0; d2 < 4; ++d2)
#pragma unroll
            for (int e = 0; e < 16; ++e) oacc[a][d2][e] = 0.f;

    for (int it = 0; it < iters; ++it) {
        const int i0t = ibase + it * 64;

        // ---- mask word: 64 i-bits for column j = j0 + jh*32 + lo ----
        const u64 wd = adjb[((size_t)(i0t >> 6)) * N + j0 + jh * 32 + lo];

        // ---- QK^T: S^T[ih*32 i][jh*32 j], 32 k-steps ----
        f32x16 sacc;
#pragma unroll
        for (int e = 0; e < 16; ++e) sacc[e] = 0.f;
        const f16* kp = kh + (size_t)(i0t + ih * 32 + lo) * D + hi * 8;
        const char* qp = Qs + (jh * 32 + lo) * QROW + hi * 16;
#pragma unroll 8
        for (int ks = 0; ks < 32; ++ks) {
            const f16x8 kf = *(const f16x8*)(kp + ks * 16);
            const f16x8 qf = *(const f16x8*)(qp + ks * 32);
            sacc = __builtin_amdgcn_mfma_f32_32x32x16_f16(kf, qf, sacc, 0, 0, 0);
        }

        // ---- mask + band stats; lane: col j = jh*32+lo, rows i = ih*32+(r&3)+8*(r>>2)+4*hi ----
        float s16[16];
        float mband = NEG;
#pragma unroll
        for (int r = 0; r < 16; ++r) {
            const int ibit = ih * 32 + (r & 3) + 8 * (r >> 2) + 4 * hi;
            const float sv = ((wd >> ibit) & 1) ? sacc[r] : NEG;
            s16[r] = sv;
            mband = fmaxf(mband, sv);
        }
        mband = fmaxf(mband, __shfl_xor(mband, 32, 64));
        float pe[16];
        float pl = 0.f;
#pragma unroll
        for (int r = 0; r < 16; ++r) {
            const float p = (s16[r] > -1e29f) ? __expf(s16[r] - mband) : 0.f;
            pe[r] = p;
            pl += p;
        }
        pl += __shfl_xor(pl, 32, 64);
        if (l < 32) {
            mstat[ih * 64 + jh * 32 + l] = mband;
            lstat[ih * 64 + jh * 32 + l] = pl;
        }
        __syncthreads();                     // [A] stats visible

        // ---- combine (wave 0, one j each) ----
        if (t < 64) {
            const float mo = mrow[t];
            const float b0 = mstat[t],      s0 = lstat[t];
            const float b1 = mstat[64 + t], s1 = lstat[64 + t];
            const float mn = fmaxf(mo, fmaxf(b0, b1));
            const float ln = lrow[t] * __expf(mo - mn)
                           + s0 * __expf(b0 - mn) + s1 * __expf(b1 - mn);
            mrow[t] = mn; lrow[t] = ln; scl[t] = __expf(mo - mn);
        }
        __syncthreads();                     // [B] m_new / scl ready

        // ---- P fix to global max + write to LDS ----
        {
            const float f = __expf(mband - mrow[jh * 32 + lo]);
#pragma unroll
            for (int g = 0; g < 4; ++g) {
                union { f16 h[4]; uint2 u2; } pc;
#pragma unroll
                for (int rr = 0; rr < 4; ++rr) pc.h[rr] = (f16)(pe[g * 4 + rr] * f);
                *(uint2*)(Psb + (jh * 32 + lo) * PROW + ih * 64 + g * 16 + hi * 8) = pc.u2;
            }
        }

        // ---- rescale O rows by scl[j] ----
#pragma unroll
        for (int a = 0; a < 2; ++a)
#pragma unroll
            for (int r = 0; r < 16; ++r) {
                const float scr = scl[a * 32 + (r & 3) + 8 * (r >> 2) + 4 * hi];
#pragma unroll
                for (int d2 = 0; d2 < 4; ++d2) oacc[a][d2][r] *= scr;
            }
        __syncthreads();                     // [C] P ready

        // ---- PV: wave w = d-band w*128; 8 C-tiles (2 jh2 x 4 dsub) ----
        f16x8 pa[2][4];
#pragma unroll
        for (int a = 0; a < 2; ++a)
#pragma unroll
            for (int ks2 = 0; ks2 < 4; ++ks2)
                pa[a][ks2] = *(const f16x8*)(Psb + (a * 32 + lo) * PROW + ks2 * 32 + hi * 16);

#pragma unroll
        for (int d2 = 0; d2 < 4; ++d2) {
            const f16* vp = vt + (size_t)(w * 128 + d2 * 32 + lo) * N + i0t + hi * 8;
#pragma unroll
            for (int ks2 = 0; ks2 < 4; ++ks2) {
                const f16x8 vf = *(const f16x8*)(vp + ks2 * 16);
#pragma unroll
                for (int a = 0; a < 2; ++a)
                    oacc[a][d2] = __builtin_amdgcn_mfma_f32_32x32x16_f16(pa[a][ks2], vf, oacc[a][d2], 0, 0, 0);
            }
        }
        __syncthreads();                     // [D] P consumed
    }

    // ---- store fp16 unnormalized partial: row j = a*32+(r&3)+8*(r>>2)+4*hi, col = w*128+d2*32+lo ----
#pragma unroll
    for (int a = 0; a < 2; ++a)
#pragma unroll
        for (int d2 = 0; d2 < 4; ++d2)
#pragma unroll
            for (int r = 0; r < 16; ++r) {
                const int row = j0 + a * 32 + (r & 3) + 8 * (r >> 2) + 4 * hi;
                pb[(size_t)row * D + w * 128 + d2 * 32 + lo] = (f16)oacc[a][d2][r];
            }
    if (t < 64) {
        float2 v; v.x = mrow[t]; v.y = lrow[t];
        ml[(size_t)ib * N + j0 + t] = v;
    }
}

// ---------------- merge the i-block partials ----------------
__global__ __launch_bounds__(256) void merge_p(
    float* __restrict__ out, const f16* __restrict__ p0,
    const f16* __restrict__ p123, const float2* __restrict__ ml, int nib)
{
    const int idx = blockIdx.x * 256 + threadIdx.x;
    const int j = idx >> 7;
    const int col = (idx & 127) * 4;

    float m_g = NEG;
    for (int ib = 0; ib < nib; ++ib) m_g = fmaxf(m_g, ml[(size_t)ib * N + j].x);
    float L = 0.f;
    float4 acc; acc.x = 0.f; acc.y = 0.f; acc.z = 0.f; acc.w = 0.f;
    for (int ib = 0; ib < nib; ++ib) {
        const float2 a = ml[(size_t)ib * N + j];
        const float e = __expf(a.x - m_g);
        L += e * a.y;
        const f16* pp = (ib == 0) ? p0 : p123 + (size_t)(ib - 1) * ((size_t)N * D);
        const f16x4 h = *(const f16x4*)(pp + (size_t)j * D + col);
        acc.x += e * (float)h.x; acc.y += e * (float)h.y;
        acc.z += e * (float)h.z; acc.w += e * (float)h.w;
    }
    const float inv = (L > 0.f) ? 1.f / L : 0.f;
    float4 r; r.x = acc.x * inv; r.y = acc.y * inv; r.z = acc.z * inv; r.w = acc.w * inv;
    ((float4*)out)[idx] = r;
}

extern "C" void kernel_launch(void* const* d_in, const int* in_sizes, int n_in,
                              void* d_out, int out_size, void* d_ws, size_t ws_size,
                              hipStream_t stream) {
    const float* ns  = (const float*)d_in[0];
    const int*   adj = (const int*)d_in[1];
    const float* Wq  = (const float*)d_in[2];
    const float* Wk  = (const float*)d_in[3];
    const float* Wv  = (const float*)d_in[4];

    char* ws = (char*)d_ws;
    f16*   Xh   = (f16*)(ws + XH_OFF);
    f16*   Wqh  = (f16*)(ws + WQH_OFF);
    f16*   Wkh  = (f16*)(ws + WKH_OFF);
    f16*   Wvh  = (f16*)(ws + WVH_OFF);
    f16*   qh   = (f16*)(ws + QH_OFF);
    f16*   kh   = (f16*)(ws + KH_OFF);
    f16*   vt   = (f16*)(ws + VT_OFF);
    f16*   p0   = (f16*)(ws + XH_OFF);          // overlays dead XH
    f16*   p123 = (f16*)(ws + P123_OFF);
    float* out  = (float*)d_out;

    const size_t need4 = P123_OFF + 3 * PART_SZ + ML_SZ + ADJ_SZ;
    int nib; size_t ml_off;
    if (ws_size >= need4) { nib = 4; ml_off = P123_OFF + 3 * PART_SZ; }
    else                  { nib = 2; ml_off = P123_OFF + 1 * PART_SZ; }
    float2* mlb  = (float2*)(ws + ml_off);
    u64*    adjb = (u64*)(ws + ml_off + ML_SZ);

    (void)hipFuncSetAttribute((const void*)attn_v9,
                              hipFuncAttributeMaxDynamicSharedMemorySize, LDSB_V9);

    cvt_fp16<<<4864, 256, 0, stream>>>(ns, Wq, Wk, Wv, Xh, Wqh, Wkh, Wvh);
    qkv_mfma<<<dim3(4, 64, 3), 256, 0, stream>>>(Xh, Wqh, Wkh, Wvh, qh, kh, vt);
    pack_adj<<<4096, 256, 0, stream>>>(adj, adjb);
    attn_v9<<<128 * nib, 256, LDSB_V9, stream>>>(qh, kh, vt, adjb, p0, p123, mlb);
    merge_p<<<4096, 256, 0, stream>>>(out, p0, p123, mlb, nib);
}